// Round 16
// baseline (32.276 us; speedup 1.0000x reference)
//
#include <hip/hip_runtime.h>

#define NPTS    8192
#define BATCH   2
#define CH      64
#define NGROUPS 50

#define TS      256                  // square tile side
#define NROW    (NPTS/TS)            // 32
#define NTILEB  (NROW*(NROW+1)/2)    // 528 triangle tiles per batch
#define MAINPB  (NTILEB*2)           // 1056 half-tiles (256i x 128j) per batch
#define MAINB   (BATCH*MAINPB)       // 2112
#define NBUCK   (BATCH*NGROUPS)      // 100
#define CORRB   (NBUCK*4)            // 400 correction blocks (dispatched FIRST)
#define GRID_T  (CORRB+MAINB)        // 2512
#define PAD     256                  // bucket capacity
#define CONVB   512                  // fsim conv blocks (32 points each)

typedef float v2f __attribute__((ext_vector_type(2)));
typedef float v4f __attribute__((ext_vector_type(4)));

// ------------- Kernel 1: Fsim packed AoS {x,y,z,|f|^2} + per-label index compaction ----
// Conv split to 512 blocks (32 pts each, 8 thr/pt) for latency hiding (was 256 @ 1.4/CU).
__global__ __launch_bounds__(256) void fsim_kernel(
    const float* __restrict__ l0, const float* __restrict__ W,
    const float* __restrict__ bias, const int* __restrict__ target,
    float4* __restrict__ fj4, int* __restrict__ gidx, int* __restrict__ gcnt)
{
    const int bid = blockIdx.x, tid = threadIdx.x;

    if (bid < CONVB) {
        __shared__ float sW[3 * CH];
        if (tid < 3 * CH) sW[tid] = W[tid];
        __syncthreads();
        const int lane = tid & 63, wave = tid >> 6;
        const int p  = lane & 7;            // point within wave (8 pts/wave)
        const int cg = lane >> 3;           // channel group (0..7), 8 ch each
        const int pt = bid * 32 + wave * 8 + p;
        const int b  = pt >> 13, n = pt & (NPTS - 1);
        const float* basep = l0 + (size_t)b * CH * NPTS + n;
        float ax = 0.f, ay = 0.f, az = 0.f;
        #pragma unroll
        for (int k = 0; k < 8; ++k) {
            int c = cg * 8 + k;
            float v = basep[(size_t)c * NPTS];
            ax = fmaf(sW[c], v, ax);
            ay = fmaf(sW[CH + c], v, ay);
            az = fmaf(sW[2*CH + c], v, az);
        }
        // reduce across the 8 channel groups (stride-8 lanes)
        ax += __shfl_down(ax,32,64); ay += __shfl_down(ay,32,64); az += __shfl_down(az,32,64);
        ax += __shfl_down(ax,16,64); ay += __shfl_down(ay,16,64); az += __shfl_down(az,16,64);
        ax += __shfl_down(ax, 8,64); ay += __shfl_down(ay, 8,64); az += __shfl_down(az, 8,64);
        if (cg == 0) {
            float X = ax + bias[0], Y = ay + bias[1], Z = az + bias[2];
            fj4[pt] = make_float4(X, Y, Z, fmaf(X, X, fmaf(Y, Y, Z * Z)));
        }
    } else {
        // ---- index compaction for bucket (b, L) ----
        const int bucket = bid - CONVB;
        const int b = bucket / NGROUPS, L = bucket % NGROUPS;
        const int tbase = b * NPTS;
        __shared__ int scnt[256];
        int cnt = 0;
        const int4* t4 = (const int4*)&target[tbase];
        #pragma unroll
        for (int k8 = 0; k8 < 8; ++k8) {
            int4 tv = t4[tid * 8 + k8];
            cnt += (tv.x == L) + (tv.y == L) + (tv.z == L) + (tv.w == L);
        }
        scnt[tid] = cnt;
        __syncthreads();
        for (int s = 1; s < 256; s <<= 1) {       // Hillis-Steele inclusive scan
            int a = (tid >= s) ? scnt[tid - s] : 0;
            __syncthreads();
            scnt[tid] += a;
            __syncthreads();
        }
        int wpos = scnt[tid] - cnt;               // stable by point index
        for (int k = 0; k < 32; ++k) {
            int idx = tid * 32 + k;
            if (target[tbase + idx] == L) {
                if (wpos < PAD) gidx[bucket * PAD + wpos] = idx;
                ++wpos;
            }
        }
        if (tid == 0) gcnt[bucket] = min(scnt[255], PAD);
    }
}

// packed inner body over an i-pair: t = si + wj - 2 fi.fj + 1 ; acc += rcp(t)^2
#define PKPAIR(NX, NY, NZ, SI, ACC)                                  \
    {                                                                \
        v2f t = SI + qww;                                            \
        t = __builtin_elementwise_fma(NX, qxx, t);                   \
        t = __builtin_elementwise_fma(NY, qyy, t);                   \
        t = __builtin_elementwise_fma(NZ, qzz, t);                   \
        v2f r;                                                       \
        r.x = __builtin_amdgcn_rcpf(t.x);                            \
        r.y = __builtin_amdgcn_rcpf(t.y);                            \
        ACC = __builtin_elementwise_fma(r, r, ACC);                  \
    }

// ------------- Kernel 2: triangle rr-sum (uniform) + bucket corrections -------------
__global__ __launch_bounds__(256, 8) void pair_kernel(
    const float4* __restrict__ fj4,
    const int* __restrict__ gidx, const int* __restrict__ gcnt,
    double* __restrict__ partials)
{
    const int bid = blockIdx.x, tid = threadIdx.x;
    __shared__ float4 sj[PAD];   // main: sjA=[0..127] {x,x,y,y}, sjB=[128..255] {z,z,w,w}; corr: 256 pts
    __shared__ double wsum[4];

    float  accv = 0.0f;
    double cadd = 0.0;

    if (bid >= CORRB) {
        // ---- uniform half-tile: 256 i's x 128 j's = 32K pairs ----
        const int mid = bid - CORRB;
        const int b   = mid / MAINPB;
        const int r   = mid % MAINPB;
        const int tau = r >> 1, half = r & 1;
        int ti = (int)(32.5f - sqrtf(32.5f * 32.5f - 2.0f * (float)tau));
        if (ti < 0) ti = 0; if (ti > NROW - 1) ti = NROW - 1;
        while ((ti + 1) * (65 - (ti + 1)) / 2 <= tau) ++ti;   // cum(r)=r*(65-r)/2
        while (ti * (65 - ti) / 2 > tau) --ti;
        const int tj = ti + (tau - ti * (65 - ti) / 2);

        const int base = b * NPTS;
        const int ib = base + ti * TS + (tid & 63) * 4;
        const float4 p0 = fj4[ib + 0], p1 = fj4[ib + 1];
        const float4 p2 = fj4[ib + 2], p3 = fj4[ib + 3];
        const v2f nx01 = {-2.f*p0.x, -2.f*p1.x}, nx23 = {-2.f*p2.x, -2.f*p3.x};
        const v2f ny01 = {-2.f*p0.y, -2.f*p1.y}, ny23 = {-2.f*p2.y, -2.f*p3.y};
        const v2f nz01 = {-2.f*p0.z, -2.f*p1.z}, nz23 = {-2.f*p2.z, -2.f*p3.z};
        const v2f si01 = {p0.w+1.f, p1.w+1.f},   si23 = {p2.w+1.f, p3.w+1.f};

        if (tid < 128) {
            // single vector load (AoS) -> duplicated split-array layout
            const float4 g = fj4[base + tj * TS + half * 128 + tid];
            sj[tid]       = make_float4(g.x, g.x, g.y, g.y);
            sj[128 + tid] = make_float4(g.z, g.z, g.w, g.w);
        }
        __syncthreads();

        const int j0 = (tid >> 6) * 32;     // this wave's 32-j slice
        const v4f* sj4 = (const v4f*)sj;
        v2f acc01 = {0.f, 0.f}, acc23 = {0.f, 0.f};
        #pragma unroll 4
        for (int jj = 0; jj < 32; ++jj) {
            const int jr = j0 + jj;
            const v4f A = sj4[jr];           // {x,x,y,y}
            const v4f B = sj4[128 + jr];     // {z,z,w,w}
            const v2f qxx = A.xy, qyy = A.zw, qzz = B.xy, qww = B.zw;
            PKPAIR(nx01, ny01, nz01, si01, acc01)
            PKPAIR(nx23, ny23, nz23, si23, acc23)
        }
        float s = (acc01.x + acc01.y) + (acc23.x + acc23.y);
        // weights reconstruct 2 * S_all(rr over full matrix incl diag)
        accv = (ti == tj) ? (2.0f * s) : (4.0f * s);
    } else {
        // ---- bucket correction: ordered same-label pairs, (t - 2rr), masked ----
        const int bucket = bid >> 2, sub = bid & 3;
        const int b = bucket / NGROUPS;
        const int cnt = gcnt[bucket];
        const int base = b * NPTS;
        {
            float4 pv = make_float4(0.f, 0.f, 0.f, 0.f);
            if (tid < cnt) {
                float4 g = fj4[base + gidx[bucket * PAD + tid]];
                pv = make_float4(g.x, g.y, g.z, 1.0f);
            }
            sj[tid] = pv;
        }
        __syncthreads();
        const int pp = sub * 64 + (tid & 63);
        const int g0 = (tid >> 6) * 64;
        if (pp < cnt) {
            const float4 a = sj[pp];
            float accB = 0.f;
            #pragma unroll 4
            for (int qq = g0; qq < g0 + 64; ++qq) {
                float4 c = sj[qq];
                float dx = a.x - c.x, dy = a.y - c.y, dz = a.z - c.z;
                float t = fmaf(dx, dx, fmaf(dy, dy, fmaf(dz, dz, 1.0f)));
                float rr = __builtin_amdgcn_rcpf(t); rr = rr * rr;
                accB = fmaf(fmaf(-2.0f, rr, t), c.w, accB);   // mask via c.w
            }
            accv = accB;
        }
        if (sub == 0 && tid == 0) {
            double c = (double)cnt;
            cadd = 2.0 * c - c * c;    // Sum_{p!=q}(d-2rr) = Sum_all(t-2rr) - c^2 + 2c
        }
    }

    // ---- block reduction -> one double, plain store ----
    #pragma unroll
    for (int o = 32; o > 0; o >>= 1) accv += __shfl_down(accv, o, 64);
    if ((tid & 63) == 0) wsum[tid >> 6] = (double)accv;
    __syncthreads();
    if (tid == 0)
        partials[bid] = (wsum[0] + wsum[1]) + (wsum[2] + wsum[3]) + cadd;
}

// ------------- Kernel 3: final reduce + scale -------------
__global__ __launch_bounds__(256) void finalize_kernel(
    const double* __restrict__ partials, float* __restrict__ out)
{
    const int tid = threadIdx.x;
    double s = 0.0;
    for (int k = tid; k < GRID_T; k += 256) s += partials[k];
    #pragma unroll
    for (int o = 32; o > 0; o >>= 1) s += __shfl_down(s, o, 64);
    __shared__ double sd[4];
    if ((tid & 63) == 0) sd[tid >> 6] = s;
    __syncthreads();
    if (tid == 0) {
        double tot = (sd[0] + sd[1]) + (sd[2] + sd[3]);
        // Sum(partials) = 2*S_all(rr) + corrections; remove 2*diag (rr(0)=1 each)
        tot -= 2.0 * (double)(BATCH * NPTS);
        out[0] = (float)(100.0 * tot / ((double)BATCH * NPTS * NPTS));
    }
}

extern "C" void kernel_launch(void* const* d_in, const int* in_sizes, int n_in,
                              void* d_out, int out_size, void* d_ws, size_t ws_size,
                              hipStream_t stream) {
    const float* l0     = (const float*)d_in[0];   // [2,64,8192]
    const float* W      = (const float*)d_in[1];   // [3,64]
    const float* bias   = (const float*)d_in[2];   // [3]
    const int*   target = (const int*)d_in[3];     // [2,8192]
    float* out = (float*)d_out;

    float4* fj4      = (float4*)d_ws;                               // 16384 * 16B
    double* partials = (double*)((char*)d_ws + BATCH * NPTS * sizeof(float4));
    int*    gidx     = (int*)((char*)partials + GRID_T * sizeof(double));
    int*    gcnt     = gidx + NBUCK * PAD;

    fsim_kernel<<<CONVB + NBUCK, 256, 0, stream>>>(l0, W, bias, target, fj4, gidx, gcnt);
    pair_kernel<<<GRID_T, 256, 0, stream>>>(fj4, gidx, gcnt, partials);
    finalize_kernel<<<1, 256, 0, stream>>>(partials, out);
}

// Round 17
// 31.701 us; speedup vs baseline: 1.0182x; 1.0182x over previous
//
#include <hip/hip_runtime.h>

#define NPTS    8192
#define BATCH   2
#define CH      64
#define NGROUPS 50

#define TS      256                  // square tile side
#define NROW    (NPTS/TS)            // 32
#define NTILEB  (NROW*(NROW+1)/2)    // 528 triangle tiles per batch
#define MAINPB  (NTILEB*2)           // 1056 half-tiles (256i x 128j) per batch
#define MAINB   (BATCH*MAINPB)       // 2112
#define NBUCK   (BATCH*NGROUPS)      // 100
#define CORRB   (NBUCK*4)            // 400 correction blocks (dispatched FIRST)
#define GRID_T  (CORRB+MAINB)        // 2512
#define PAD     256                  // bucket capacity

typedef float v2f __attribute__((ext_vector_type(2)));
typedef float v4f __attribute__((ext_vector_type(4)));

// ------------- Kernel 1: Fsim (SoA + |f|^2) + per-label index compaction -------------
__global__ __launch_bounds__(256) void fsim_kernel(
    const float* __restrict__ l0, const float* __restrict__ W,
    const float* __restrict__ bias, const int* __restrict__ target,
    float* __restrict__ fx, float* __restrict__ fy, float* __restrict__ fz,
    float* __restrict__ fw, int* __restrict__ gidx, int* __restrict__ gcnt)
{
    const int bid = blockIdx.x, tid = threadIdx.x;

    if (bid < 256) {
        __shared__ float sW[3 * CH];
        if (tid < 3 * CH) sW[tid] = W[tid];
        __syncthreads();
        const int lane = tid & 63, wave = tid >> 6;
        const int p = lane & 15, cg = lane >> 4;
        const int pt = bid * 64 + wave * 16 + p;
        const int b = pt >> 13, n = pt & (NPTS - 1);
        const float* basep = l0 + (size_t)b * CH * NPTS + n;
        float ax = 0.f, ay = 0.f, az = 0.f;
        #pragma unroll
        for (int k = 0; k < 16; ++k) {
            int c = cg * 16 + k;
            float v = basep[(size_t)c * NPTS];
            ax = fmaf(sW[c], v, ax);
            ay = fmaf(sW[CH + c], v, ay);
            az = fmaf(sW[2*CH + c], v, az);
        }
        ax += __shfl_down(ax,32,64); ay += __shfl_down(ay,32,64); az += __shfl_down(az,32,64);
        ax += __shfl_down(ax,16,64); ay += __shfl_down(ay,16,64); az += __shfl_down(az,16,64);
        if (cg == 0) {
            float X = ax + bias[0], Y = ay + bias[1], Z = az + bias[2];
            fx[pt] = X; fy[pt] = Y; fz[pt] = Z;
            fw[pt] = fmaf(X, X, fmaf(Y, Y, Z * Z));
        }
    } else {
        // ---- index compaction for bucket (b, L): wave-shfl scan (1 barrier) ----
        const int bucket = bid - 256;
        const int b = bucket / NGROUPS, L = bucket % NGROUPS;
        const int tbase = b * NPTS;
        const int lane = tid & 63, wave = tid >> 6;
        __shared__ int wtot[4];

        int cnt = 0;
        const int4* t4 = (const int4*)&target[tbase];
        #pragma unroll
        for (int k8 = 0; k8 < 8; ++k8) {
            int4 tv = t4[tid * 8 + k8];
            cnt += (tv.x == L) + (tv.y == L) + (tv.z == L) + (tv.w == L);
        }
        // inclusive scan within wave (no barriers)
        int v = cnt;
        #pragma unroll
        for (int s = 1; s < 64; s <<= 1) {
            int u = __shfl_up(v, s, 64);
            v += (lane >= s) ? u : 0;
        }
        if (lane == 63) wtot[wave] = v;
        __syncthreads();
        int wbase = 0;
        #pragma unroll
        for (int w = 0; w < 4; ++w) wbase += (w < wave) ? wtot[w] : 0;
        int wpos = wbase + v - cnt;               // exclusive prefix, stable order
        for (int k = 0; k < 32; ++k) {
            int idx = tid * 32 + k;
            if (target[tbase + idx] == L) {
                if (wpos < PAD) gidx[bucket * PAD + wpos] = idx;
                ++wpos;
            }
        }
        if (tid == 0)
            gcnt[bucket] = min(wtot[0] + wtot[1] + wtot[2] + wtot[3], PAD);
    }
}

// packed inner body over an i-pair: t = si + wj - 2 fi.fj + 1 ; acc += rcp(t)^2
#define PKPAIR(NX, NY, NZ, SI, ACC)                                  \
    {                                                                \
        v2f t = SI + qww;                                            \
        t = __builtin_elementwise_fma(NX, qxx, t);                   \
        t = __builtin_elementwise_fma(NY, qyy, t);                   \
        t = __builtin_elementwise_fma(NZ, qzz, t);                   \
        v2f r;                                                       \
        r.x = __builtin_amdgcn_rcpf(t.x);                            \
        r.y = __builtin_amdgcn_rcpf(t.y);                            \
        ACC = __builtin_elementwise_fma(r, r, ACC);                  \
    }

// ------------- Kernel 2: triangle rr-sum (uniform) + bucket corrections -------------
__global__ __launch_bounds__(256, 8) void pair_kernel(
    const float* __restrict__ fx, const float* __restrict__ fy,
    const float* __restrict__ fz, const float* __restrict__ fw,
    const int* __restrict__ gidx, const int* __restrict__ gcnt,
    double* __restrict__ partials)
{
    const int bid = blockIdx.x, tid = threadIdx.x;
    __shared__ float4 sj[PAD];   // main: sjA=[0..127] {x,x,y,y}, sjB=[128..255] {z,z,w,w}; corr: 256 pts
    __shared__ double wsum[4];

    float  accv = 0.0f;
    double cadd = 0.0;

    if (bid >= CORRB) {
        // ---- uniform half-tile: 256 i's x 128 j's = 32K pairs ----
        const int mid = bid - CORRB;
        const int b   = mid / MAINPB;
        const int r   = mid % MAINPB;
        const int tau = r >> 1, half = r & 1;
        int ti = (int)(32.5f - sqrtf(32.5f * 32.5f - 2.0f * (float)tau));
        if (ti < 0) ti = 0; if (ti > NROW - 1) ti = NROW - 1;
        while ((ti + 1) * (65 - (ti + 1)) / 2 <= tau) ++ti;   // cum(r)=r*(65-r)/2
        while (ti * (65 - ti) / 2 > tau) --ti;
        const int tj = ti + (tau - ti * (65 - ti) / 2);

        const int base = b * NPTS;
        const int ib = base + ti * TS + (tid & 63) * 4;
        const float4 vx = *(const float4*)&fx[ib];
        const float4 vy = *(const float4*)&fy[ib];
        const float4 vz = *(const float4*)&fz[ib];
        const float4 vw = *(const float4*)&fw[ib];
        const v2f nx01 = {-2.f*vx.x, -2.f*vx.y}, nx23 = {-2.f*vx.z, -2.f*vx.w};
        const v2f ny01 = {-2.f*vy.x, -2.f*vy.y}, ny23 = {-2.f*vy.z, -2.f*vy.w};
        const v2f nz01 = {-2.f*vz.x, -2.f*vz.y}, nz23 = {-2.f*vz.z, -2.f*vz.w};
        const v2f si01 = {vw.x+1.f, vw.y+1.f},   si23 = {vw.z+1.f, vw.w+1.f};

        if (tid < 128) {
            const int k = base + tj * TS + half * 128 + tid;
            const float X = fx[k], Y = fy[k], Z = fz[k], Wq = fw[k];
            // split-array duplicated layout: contiguous writes (no bank conflicts)
            sj[tid]       = make_float4(X, X, Y, Y);
            sj[128 + tid] = make_float4(Z, Z, Wq, Wq);
        }
        __syncthreads();

        const int j0 = (tid >> 6) * 32;     // this wave's 32-j slice
        const v4f* sj4 = (const v4f*)sj;
        v2f acc01 = {0.f, 0.f}, acc23 = {0.f, 0.f};
        #pragma unroll 4
        for (int jj = 0; jj < 32; ++jj) {
            const int jr = j0 + jj;
            const v4f A = sj4[jr];           // {x,x,y,y}
            const v4f B = sj4[128 + jr];     // {z,z,w,w}
            const v2f qxx = A.xy, qyy = A.zw, qzz = B.xy, qww = B.zw;
            PKPAIR(nx01, ny01, nz01, si01, acc01)
            PKPAIR(nx23, ny23, nz23, si23, acc23)
        }
        float s = (acc01.x + acc01.y) + (acc23.x + acc23.y);
        // weights reconstruct 2 * S_all(rr over full matrix incl diag)
        accv = (ti == tj) ? (2.0f * s) : (4.0f * s);
    } else {
        // ---- bucket correction: ordered same-label pairs, (t - 2rr), masked ----
        const int bucket = bid >> 2, sub = bid & 3;
        const int b = bucket / NGROUPS;
        const int cnt = gcnt[bucket];
        const int base = b * NPTS;
        {
            float4 pv = make_float4(0.f, 0.f, 0.f, 0.f);
            if (tid < cnt) {
                int ix = base + gidx[bucket * PAD + tid];
                pv = make_float4(fx[ix], fy[ix], fz[ix], 1.0f);
            }
            sj[tid] = pv;
        }
        __syncthreads();
        const int pp = sub * 64 + (tid & 63);
        const int g0 = (tid >> 6) * 64;
        if (pp < cnt) {
            const float4 a = sj[pp];
            float accB = 0.f;
            #pragma unroll 4
            for (int qq = g0; qq < g0 + 64; ++qq) {
                float4 c = sj[qq];
                float dx = a.x - c.x, dy = a.y - c.y, dz = a.z - c.z;
                float t = fmaf(dx, dx, fmaf(dy, dy, fmaf(dz, dz, 1.0f)));
                float rr = __builtin_amdgcn_rcpf(t); rr = rr * rr;
                accB = fmaf(fmaf(-2.0f, rr, t), c.w, accB);   // mask via c.w
            }
            accv = accB;
        }
        if (sub == 0 && tid == 0) {
            double c = (double)cnt;
            cadd = 2.0 * c - c * c;    // Sum_{p!=q}(d-2rr) = Sum_all(t-2rr) - c^2 + 2c
        }
    }

    // ---- block reduction -> one double, plain store ----
    #pragma unroll
    for (int o = 32; o > 0; o >>= 1) accv += __shfl_down(accv, o, 64);
    if ((tid & 63) == 0) wsum[tid >> 6] = (double)accv;
    __syncthreads();
    if (tid == 0)
        partials[bid] = (wsum[0] + wsum[1]) + (wsum[2] + wsum[3]) + cadd;
}

// ------------- Kernel 3: final reduce + scale -------------
__global__ __launch_bounds__(256) void finalize_kernel(
    const double* __restrict__ partials, float* __restrict__ out)
{
    const int tid = threadIdx.x;
    double s = 0.0;
    for (int k = tid; k < GRID_T; k += 256) s += partials[k];
    #pragma unroll
    for (int o = 32; o > 0; o >>= 1) s += __shfl_down(s, o, 64);
    __shared__ double sd[4];
    if ((tid & 63) == 0) sd[tid >> 6] = s;
    __syncthreads();
    if (tid == 0) {
        double tot = (sd[0] + sd[1]) + (sd[2] + sd[3]);
        // Sum(partials) = 2*S_all(rr) + corrections; remove 2*diag (rr(0)=1 each)
        tot -= 2.0 * (double)(BATCH * NPTS);
        out[0] = (float)(100.0 * tot / ((double)BATCH * NPTS * NPTS));
    }
}

extern "C" void kernel_launch(void* const* d_in, const int* in_sizes, int n_in,
                              void* d_out, int out_size, void* d_ws, size_t ws_size,
                              hipStream_t stream) {
    const float* l0     = (const float*)d_in[0];   // [2,64,8192]
    const float* W      = (const float*)d_in[1];   // [3,64]
    const float* bias   = (const float*)d_in[2];   // [3]
    const int*   target = (const int*)d_in[3];     // [2,8192]
    float* out = (float*)d_out;

    float* fx = (float*)d_ws;                      // 16384 floats each
    float* fy = fx + BATCH * NPTS;
    float* fz = fy + BATCH * NPTS;
    float* fw = fz + BATCH * NPTS;
    double* partials = (double*)((char*)d_ws + 4 * BATCH * NPTS * sizeof(float));
    int* gidx = (int*)((char*)partials + GRID_T * sizeof(double));
    int* gcnt = gidx + NBUCK * PAD;

    fsim_kernel<<<256 + NBUCK, 256, 0, stream>>>(l0, W, bias, target,
                                                 fx, fy, fz, fw, gidx, gcnt);
    pair_kernel<<<GRID_T, 256, 0, stream>>>(fx, fy, fz, fw, gidx, gcnt, partials);
    finalize_kernel<<<1, 256, 0, stream>>>(partials, out);
}

// Round 19
// 31.520 us; speedup vs baseline: 1.0240x; 1.0057x over previous
//
#include <hip/hip_runtime.h>

#define NPTS    8192
#define BATCH   2
#define CH      64
#define NGROUPS 50

#define TS      256                  // square tile side
#define NROW    (NPTS/TS)            // 32
#define NTILEB  (NROW*(NROW+1)/2)    // 528 triangle tiles per batch
#define MAINPB  (NTILEB*2)           // 1056 half-tiles (256i x 128j) per batch
#define MAINB   (BATCH*MAINPB)       // 2112
#define NBUCK   (BATCH*NGROUPS)      // 100
#define CORRB   (NBUCK*4)            // 400 correction blocks (dispatched FIRST)
#define GRID_T  (CORRB+MAINB)        // 2512
#define PAD     256                  // bucket capacity

typedef float v2f __attribute__((ext_vector_type(2)));
typedef float v4f __attribute__((ext_vector_type(4)));

// ------------- Kernel 1: Fsim (SoA + |f|^2) + per-label index compaction -------------
__global__ __launch_bounds__(256) void fsim_kernel(
    const float* __restrict__ l0, const float* __restrict__ W,
    const float* __restrict__ bias, const int* __restrict__ target,
    float* __restrict__ fx, float* __restrict__ fy, float* __restrict__ fz,
    float* __restrict__ fw, int* __restrict__ gidx, int* __restrict__ gcnt)
{
    const int bid = blockIdx.x, tid = threadIdx.x;

    if (bid < 256) {
        __shared__ float sW[3 * CH];
        if (tid < 3 * CH) sW[tid] = W[tid];
        __syncthreads();
        const int lane = tid & 63, wave = tid >> 6;
        const int p = lane & 15, cg = lane >> 4;
        const int pt = bid * 64 + wave * 16 + p;
        const int b = pt >> 13, n = pt & (NPTS - 1);
        const float* basep = l0 + (size_t)b * CH * NPTS + n;
        float ax = 0.f, ay = 0.f, az = 0.f;
        #pragma unroll
        for (int k = 0; k < 16; ++k) {
            int c = cg * 16 + k;
            float v = basep[(size_t)c * NPTS];
            ax = fmaf(sW[c], v, ax);
            ay = fmaf(sW[CH + c], v, ay);
            az = fmaf(sW[2*CH + c], v, az);
        }
        ax += __shfl_down(ax,32,64); ay += __shfl_down(ay,32,64); az += __shfl_down(az,32,64);
        ax += __shfl_down(ax,16,64); ay += __shfl_down(ay,16,64); az += __shfl_down(az,16,64);
        if (cg == 0) {
            float X = ax + bias[0], Y = ay + bias[1], Z = az + bias[2];
            fx[pt] = X; fy[pt] = Y; fz[pt] = Z;
            fw[pt] = fmaf(X, X, fmaf(Y, Y, Z * Z));
        }
    } else {
        // ---- index compaction for bucket (b, L): wave-shfl scan (1 barrier) ----
        const int bucket = bid - 256;
        const int b = bucket / NGROUPS, L = bucket % NGROUPS;
        const int tbase = b * NPTS;
        const int lane = tid & 63, wave = tid >> 6;
        __shared__ int wtot[4];

        int cnt = 0;
        const int4* t4 = (const int4*)&target[tbase];
        #pragma unroll
        for (int k8 = 0; k8 < 8; ++k8) {
            int4 tv = t4[tid * 8 + k8];
            cnt += (tv.x == L) + (tv.y == L) + (tv.z == L) + (tv.w == L);
        }
        // inclusive scan within wave (no barriers)
        int v = cnt;
        #pragma unroll
        for (int s = 1; s < 64; s <<= 1) {
            int u = __shfl_up(v, s, 64);
            v += (lane >= s) ? u : 0;
        }
        if (lane == 63) wtot[wave] = v;
        __syncthreads();
        int wbase = 0;
        #pragma unroll
        for (int w = 0; w < 4; ++w) wbase += (w < wave) ? wtot[w] : 0;
        int wpos = wbase + v - cnt;               // exclusive prefix, stable order
        for (int k = 0; k < 32; ++k) {
            int idx = tid * 32 + k;
            if (target[tbase + idx] == L) {
                if (wpos < PAD) gidx[bucket * PAD + wpos] = idx;
                ++wpos;
            }
        }
        if (tid == 0)
            gcnt[bucket] = min(wtot[0] + wtot[1] + wtot[2] + wtot[3], PAD);
    }
}

// packed inner body over an i-pair: t = si + wj - 2 fi.fj + 1 ; acc += rcp(t)^2
#define PKPAIR(NX, NY, NZ, SI, ACC)                                  \
    {                                                                \
        v2f t = SI + qww;                                            \
        t = __builtin_elementwise_fma(NX, qxx, t);                   \
        t = __builtin_elementwise_fma(NY, qyy, t);                   \
        t = __builtin_elementwise_fma(NZ, qzz, t);                   \
        v2f r;                                                       \
        r.x = __builtin_amdgcn_rcpf(t.x);                            \
        r.y = __builtin_amdgcn_rcpf(t.y);                            \
        ACC = __builtin_elementwise_fma(r, r, ACC);                  \
    }

// ------------- Kernel 2: triangle rr-sum (uniform) + bucket corrections -------------
__global__ __launch_bounds__(256, 8) void pair_kernel(
    const float* __restrict__ fx, const float* __restrict__ fy,
    const float* __restrict__ fz, const float* __restrict__ fw,
    const int* __restrict__ gidx, const int* __restrict__ gcnt,
    double* __restrict__ partials)
{
    const int bid = blockIdx.x, tid = threadIdx.x;
    __shared__ float4 sj[PAD];   // main: sjA=[0..127] {x,x,y,y}, sjB=[128..255] {z,z,w,w}; corr: 256 pts
    __shared__ double wsum[4];

    float  accv = 0.0f;
    double cadd = 0.0;

    if (bid >= CORRB) {
        // ---- uniform half-tile: 256 i's x 128 j's = 32K pairs ----
        const int mid = bid - CORRB;
        const int b   = mid / MAINPB;
        const int r   = mid % MAINPB;
        const int tau = r >> 1, half = r & 1;
        int ti = (int)(32.5f - sqrtf(32.5f * 32.5f - 2.0f * (float)tau));
        if (ti < 0) ti = 0; if (ti > NROW - 1) ti = NROW - 1;
        while ((ti + 1) * (65 - (ti + 1)) / 2 <= tau) ++ti;   // cum(r)=r*(65-r)/2
        while (ti * (65 - ti) / 2 > tau) --ti;
        const int tj = ti + (tau - ti * (65 - ti) / 2);

        const int base = b * NPTS;
        const int ib = base + ti * TS + (tid & 63) * 4;
        const float4 vx = *(const float4*)&fx[ib];
        const float4 vy = *(const float4*)&fy[ib];
        const float4 vz = *(const float4*)&fz[ib];
        const float4 vw = *(const float4*)&fw[ib];
        const v2f nx01 = {-2.f*vx.x, -2.f*vx.y}, nx23 = {-2.f*vx.z, -2.f*vx.w};
        const v2f ny01 = {-2.f*vy.x, -2.f*vy.y}, ny23 = {-2.f*vy.z, -2.f*vy.w};
        const v2f nz01 = {-2.f*vz.x, -2.f*vz.y}, nz23 = {-2.f*vz.z, -2.f*vz.w};
        const v2f si01 = {vw.x+1.f, vw.y+1.f},   si23 = {vw.z+1.f, vw.w+1.f};

        if (tid < 128) {
            const int k = base + tj * TS + half * 128 + tid;
            const float X = fx[k], Y = fy[k], Z = fz[k], Wq = fw[k];
            // split-array duplicated layout: contiguous writes (no bank conflicts)
            sj[tid]       = make_float4(X, X, Y, Y);
            sj[128 + tid] = make_float4(Z, Z, Wq, Wq);
        }
        __syncthreads();

        const int j0 = (tid >> 6) * 32;     // this wave's 32-j slice
        const v4f* sj4 = (const v4f*)sj;
        v2f acc01 = {0.f, 0.f}, acc23 = {0.f, 0.f};
        #pragma unroll 4
        for (int jj = 0; jj < 32; ++jj) {
            const int jr = j0 + jj;
            const v4f A = sj4[jr];           // {x,x,y,y}
            const v4f B = sj4[128 + jr];     // {z,z,w,w}
            const v2f qxx = A.xy, qyy = A.zw, qzz = B.xy, qww = B.zw;
            PKPAIR(nx01, ny01, nz01, si01, acc01)
            PKPAIR(nx23, ny23, nz23, si23, acc23)
        }
        float s = (acc01.x + acc01.y) + (acc23.x + acc23.y);
        // weights reconstruct 2 * S_all(rr over full matrix incl diag)
        accv = (ti == tj) ? (2.0f * s) : (4.0f * s);
    } else {
        // ---- bucket correction: ordered same-label pairs, (t - 2rr), masked ----
        const int bucket = bid >> 2, sub = bid & 3;
        const int b = bucket / NGROUPS;
        const int cnt = gcnt[bucket];
        const int base = b * NPTS;
        {
            float4 pv = make_float4(0.f, 0.f, 0.f, 0.f);
            if (tid < cnt) {
                int ix = base + gidx[bucket * PAD + tid];
                pv = make_float4(fx[ix], fy[ix], fz[ix], 1.0f);
            }
            sj[tid] = pv;
        }
        __syncthreads();
        const int pp = sub * 64 + (tid & 63);
        const int g0 = (tid >> 6) * 64;
        if (pp < cnt) {
            const float4 a = sj[pp];
            float accB = 0.f;
            #pragma unroll 4
            for (int qq = g0; qq < g0 + 64; ++qq) {
                float4 c = sj[qq];
                float dx = a.x - c.x, dy = a.y - c.y, dz = a.z - c.z;
                float t = fmaf(dx, dx, fmaf(dy, dy, fmaf(dz, dz, 1.0f)));
                float rr = __builtin_amdgcn_rcpf(t); rr = rr * rr;
                accB = fmaf(fmaf(-2.0f, rr, t), c.w, accB);   // mask via c.w
            }
            accv = accB;
        }
        if (sub == 0 && tid == 0) {
            double c = (double)cnt;
            cadd = 2.0 * c - c * c;    // Sum_{p!=q}(d-2rr) = Sum_all(t-2rr) - c^2 + 2c
        }
    }

    // ---- block reduction -> one double, plain store ----
    #pragma unroll
    for (int o = 32; o > 0; o >>= 1) accv += __shfl_down(accv, o, 64);
    if ((tid & 63) == 0) wsum[tid >> 6] = (double)accv;
    __syncthreads();
    if (tid == 0)
        partials[bid] = (wsum[0] + wsum[1]) + (wsum[2] + wsum[3]) + cadd;
}

// ------------- Kernel 3: final reduce + scale -------------
__global__ __launch_bounds__(256) void finalize_kernel(
    const double* __restrict__ partials, float* __restrict__ out)
{
    const int tid = threadIdx.x;
    double s = 0.0;
    for (int k = tid; k < GRID_T; k += 256) s += partials[k];
    #pragma unroll
    for (int o = 32; o > 0; o >>= 1) s += __shfl_down(s, o, 64);
    __shared__ double sd[4];
    if ((tid & 63) == 0) sd[tid >> 6] = s;
    __syncthreads();
    if (tid == 0) {
        double tot = (sd[0] + sd[1]) + (sd[2] + sd[3]);
        // Sum(partials) = 2*S_all(rr) + corrections; remove 2*diag (rr(0)=1 each)
        tot -= 2.0 * (double)(BATCH * NPTS);
        out[0] = (float)(100.0 * tot / ((double)BATCH * NPTS * NPTS));
    }
}

extern "C" void kernel_launch(void* const* d_in, const int* in_sizes, int n_in,
                              void* d_out, int out_size, void* d_ws, size_t ws_size,
                              hipStream_t stream) {
    const float* l0     = (const float*)d_in[0];   // [2,64,8192]
    const float* W      = (const float*)d_in[1];   // [3,64]
    const float* bias   = (const float*)d_in[2];   // [3]
    const int*   target = (const int*)d_in[3];     // [2,8192]
    float* out = (float*)d_out;

    float* fx = (float*)d_ws;                      // 16384 floats each
    float* fy = fx + BATCH * NPTS;
    float* fz = fy + BATCH * NPTS;
    float* fw = fz + BATCH * NPTS;
    double* partials = (double*)((char*)d_ws + 4 * BATCH * NPTS * sizeof(float));
    int* gidx = (int*)((char*)partials + GRID_T * sizeof(double));
    int* gcnt = gidx + NBUCK * PAD;

    fsim_kernel<<<256 + NBUCK, 256, 0, stream>>>(l0, W, bias, target,
                                                 fx, fy, fz, fw, gidx, gcnt);
    pair_kernel<<<GRID_T, 256, 0, stream>>>(fx, fy, fz, fw, gidx, gcnt, partials);
    finalize_kernel<<<1, 256, 0, stream>>>(partials, out);
}